// Round 11
// baseline (849.690 us; speedup 1.0000x reference)
//
#include <hip/hip_runtime.h>
#include <cstdint>
#include <cstddef>

typedef float f32x4 __attribute__((ext_vector_type(4)));
typedef float f32x2 __attribute__((ext_vector_type(2)));
typedef short s16x8 __attribute__((ext_vector_type(8)));
typedef unsigned short u16;

static __device__ __forceinline__ u16 f2bf(float f) {
    uint32_t x = __float_as_uint(f);
    x += 0x7fffu + ((x >> 16) & 1u);   // round-to-nearest-even to bf16
    return (u16)(x >> 16);
}
static __device__ __forceinline__ float bf2f(u16 h) {
    return __uint_as_float(((uint32_t)h) << 16);
}

// Raw barrier with ONLY an LDS drain (no vmcnt) — prefetch loads / hseq
// stores stay in flight across the per-step barriers.
static __device__ __forceinline__ void bar_lds() {
    asm volatile("s_waitcnt lgkmcnt(0)" ::: "memory");
    __builtin_amdgcn_s_barrier();
    asm volatile("" ::: "memory");
}

// ---------------- zero the pipeline flags (every launch; replay-safe) ------
__global__ void k_zero(int* __restrict__ p, int n) {
    int i = blockIdx.x * 256 + threadIdx.x;
    if (i < n) p[i] = 0;
}

// ---------------- split fp32 -> bf16 hi/lo ----------------
__global__ void k_split(const float* __restrict__ src, u16* __restrict__ hi,
                        u16* __restrict__ lo, int n) {
    int i = blockIdx.x * 256 + threadIdx.x;
    if (i < n) {
        float f = src[i];
        u16 h = f2bf(f);
        hi[i] = h;
        lo[i] = f2bf(f - bf2f(h));
    }
}

// ---------------- split-bf16 GEMM (layer-0 input projection) ----------------
__global__ __launch_bounds__(256, 2)
void k_gemm(const float* __restrict__ A, const u16* __restrict__ Wh,
            const u16* __restrict__ Wl, const float* __restrict__ bias,
            float* __restrict__ C, int K) {
    __shared__ __align__(16) u16 sm[32768];   // 64 KB

    const int tid  = threadIdx.x;
    const int lane = tid & 63;
    const int wave = tid >> 6;
    const int wm = wave >> 1, wn = wave & 1;

    int g = blockIdx.x;                 // 0..767
    int xcd = g & 7, ix = g >> 3;       // 96 per xcd
    int q3 = ix / 3;
    int mb = xcd + 8 * q3;              // 0..255
    int nb = ix - 3 * q3;               // 0..2
    const long m0 = (long)mb * 128;
    const int  n0 = nb * 128;

    f32x4 acc[4][4];
    const f32x4 vzero = {0.f, 0.f, 0.f, 0.f};
#pragma unroll
    for (int i = 0; i < 4; ++i)
#pragma unroll
        for (int j = 0; j < 4; ++j) acc[i][j] = vzero;

    const int ar = tid >> 1;
    const int ac = (tid & 1) * 16;
    const float* aptr = A + (m0 + ar) * (long)K + ac;
    const int br = tid >> 2;
    const int bc = (tid & 3) * 8;
    const u16* bhp = Wh + (long)(n0 + br) * K + bc;
    const u16* blp = Wl + (long)(n0 + br) * K + bc;

    const int ksteps = K >> 5;
    f32x4 a0, a1, a2, a3;

    {
        a0 = *(const f32x4*)(aptr + 0);
        a1 = *(const f32x4*)(aptr + 4);
        a2 = *(const f32x4*)(aptr + 8);
        a3 = *(const f32x4*)(aptr + 12);
#pragma unroll
        for (int c = 0; c < 2; ++c) {
            const u16* sh = bhp + (long)(c * 64) * K;
            const u16* sl = blp + (long)(c * 64) * K;
            u16* dh = &sm[8192  + c * 2048 + wave * 512];
            u16* dl = &sm[12288 + c * 2048 + wave * 512];
            __builtin_amdgcn_global_load_lds((const __attribute__((address_space(1))) void*)sh,
                                             (__attribute__((address_space(3))) void*)dh, 16, 0, 0);
            __builtin_amdgcn_global_load_lds((const __attribute__((address_space(1))) void*)sl,
                                             (__attribute__((address_space(3))) void*)dl, 16, 0, 0);
        }
        float fr[16] = {a0.x,a0.y,a0.z,a0.w, a1.x,a1.y,a1.z,a1.w,
                        a2.x,a2.y,a2.z,a2.w, a3.x,a3.y,a3.z,a3.w};
        s16x8 h0, h1, l0, l1;
#pragma unroll
        for (int i = 0; i < 8; ++i) {
            u16 hh = f2bf(fr[i]);     h0[i] = (short)hh; l0[i] = (short)f2bf(fr[i] - bf2f(hh));
            u16 hh2 = f2bf(fr[8+i]);  h1[i] = (short)hh2; l1[i] = (short)f2bf(fr[8+i] - bf2f(hh2));
        }
        u16* dh = &sm[ar * 32 + ac];
        u16* dl = &sm[4096 + ar * 32 + ac];
        *(s16x8*)dh = h0; *(s16x8*)(dh + 8) = h1;
        *(s16x8*)dl = l0; *(s16x8*)(dl + 8) = l1;
    }
    __syncthreads();

    for (int ks = 0; ks < ksteps; ++ks) {
        const int cur = ks & 1, nxt = cur ^ 1;
        const bool more = (ks + 1 < ksteps);
        if (more) {
            const int k0 = (ks + 1) << 5;
            a0 = *(const f32x4*)(aptr + k0 + 0);
            a1 = *(const f32x4*)(aptr + k0 + 4);
            a2 = *(const f32x4*)(aptr + k0 + 8);
            a3 = *(const f32x4*)(aptr + k0 + 12);
#pragma unroll
            for (int c = 0; c < 2; ++c) {
                const u16* sh = bhp + (long)(c * 64) * K + k0;
                const u16* sl = blp + (long)(c * 64) * K + k0;
                u16* dh = &sm[nxt * 16384 + 8192  + c * 2048 + wave * 512];
                u16* dl = &sm[nxt * 16384 + 12288 + c * 2048 + wave * 512];
                __builtin_amdgcn_global_load_lds((const __attribute__((address_space(1))) void*)sh,
                                                 (__attribute__((address_space(3))) void*)dh, 16, 0, 0);
                __builtin_amdgcn_global_load_lds((const __attribute__((address_space(1))) void*)sl,
                                                 (__attribute__((address_space(3))) void*)dl, 16, 0, 0);
            }
        }
        {
            const u16* base = &sm[cur * 16384];
            const int koff = (lane >> 4) * 8;
            const int rsel = lane & 15;
            s16x8 ah[4], al[4];
#pragma unroll
            for (int f = 0; f < 4; ++f) {
                int row = wm * 64 + f * 16 + rsel;
                ah[f] = *(const s16x8*)&base[row * 32 + koff];
                al[f] = *(const s16x8*)&base[4096 + row * 32 + koff];
            }
#pragma unroll
            for (int j = 0; j < 4; ++j) {
                int row = wn * 64 + j * 16 + rsel;
                s16x8 bh = *(const s16x8*)&base[8192  + row * 32 + koff];
                s16x8 bl = *(const s16x8*)&base[12288 + row * 32 + koff];
#pragma unroll
                for (int f = 0; f < 4; ++f) {
                    acc[f][j] = __builtin_amdgcn_mfma_f32_16x16x32_bf16(ah[f], bh, acc[f][j], 0, 0, 0);
                    acc[f][j] = __builtin_amdgcn_mfma_f32_16x16x32_bf16(ah[f], bl, acc[f][j], 0, 0, 0);
                    acc[f][j] = __builtin_amdgcn_mfma_f32_16x16x32_bf16(al[f], bh, acc[f][j], 0, 0, 0);
                }
            }
        }
        if (more) {
            float fr[16] = {a0.x,a0.y,a0.z,a0.w, a1.x,a1.y,a1.z,a1.w,
                            a2.x,a2.y,a2.z,a2.w, a3.x,a3.y,a3.z,a3.w};
            s16x8 h0, h1, l0, l1;
#pragma unroll
            for (int i = 0; i < 8; ++i) {
                u16 hh = f2bf(fr[i]);     h0[i] = (short)hh; l0[i] = (short)f2bf(fr[i] - bf2f(hh));
                u16 hh2 = f2bf(fr[8+i]);  h1[i] = (short)hh2; l1[i] = (short)f2bf(fr[8+i] - bf2f(hh2));
            }
            u16* dh = &sm[nxt * 16384 + ar * 32 + ac];
            u16* dl = &sm[nxt * 16384 + 4096 + ar * 32 + ac];
            *(s16x8*)dh = h0; *(s16x8*)(dh + 8) = h1;
            *(s16x8*)dl = l0; *(s16x8*)(dl + 8) = l1;
        }
        __syncthreads();
    }

    const int r0 = (lane >> 4) << 2;
    const int cn = lane & 15;
#pragma unroll
    for (int f = 0; f < 4; ++f) {
        const long mrow = m0 + wm * 64 + f * 16 + r0;
#pragma unroll
        for (int j = 0; j < 4; ++j) {
            const int n = n0 + wn * 64 + j * 16 + cn;
            const float bv = bias[n];
            float* o = C + mrow * 384 + n;
#pragma unroll
            for (int jj = 0; jj < 4; ++jj) o[(long)jj * 384] = acc[f][j][jj] + bv;
        }
    }
}

// =================== fused pipeline kernel (r5 structure, 2 batches/block) ==
// grid = 256 blocks x 512 threads, 1 block/CU (LDS-forced).
//   blocks   0..31 : L0 recurrence, batches {2b, 2b+1}, flag per 16 steps
//   blocks  32..63 : L1 recurrence, batches {2b, 2b+1} + MLP heads
//   blocks  64..255: 192 GEMM workers: xg1 = h1 @ w_ih1^T + b_ih1
//
// Per step: phase A (all 8 waves) runs the r5 dot for BOTH batches (weights
// shared in VGPR); phase B runs batch0 on tid<128 and batch1 on tid 128..255
// (parallel across SIMDs). Barriers/latency per step are paid ONCE for two
// batches -> ~1.5x per-batch step amortization. Flag/vmcnt discipline is
// per-thread identical to r5.

struct SmemRecur { float hsh[2][128]; float hp[2][8][384]; };
struct SmemGemm  { u16 ah[16 * 128]; u16 al[16 * 128]; };
union Smem {
    SmemRecur r;
    SmemGemm  g;
    char force_one_block_per_cu[98304];   // 96KB: strictly 1 block/CU
};

#define R_ISSUE(BUF, G) do {                                                  \
    const int _G = (G);                                                       \
    if (_G < 128 && tid < 256) {                                              \
        if (!isL0 && (_G & 3) == 0) {                                         \
            if ((tid & 63) == 0) {                                            \
                while (atomicAdd(&waitflag[b2 * 32 + (_G >> 2)], 0) == 0)     \
                    __builtin_amdgcn_s_sleep(8);                              \
            }                                                                 \
            __threadfence();                                                  \
        }                                                                     \
        const float* _p = xgb2 + (size_t)(4 * _G) * 384 + (tid & 127);        \
        BUF[0] = _p[0];    BUF[1] = _p[128];   BUF[2]  = _p[256];             \
        BUF[3] = _p[384];  BUF[4] = _p[512];   BUF[5]  = _p[640];             \
        BUF[6] = _p[768];  BUF[7] = _p[896];   BUF[8]  = _p[1024];            \
        BUF[9] = _p[1152]; BUF[10] = _p[1280]; BUF[11] = _p[1408];            \
    } } while (0)

#define R_STEP(T, BUF, J) do {                                                \
    const int _t = (T);                                                       \
    _Pragma("unroll")                                                         \
    for (int _bb = 0; _bb < 2; ++_bb) {                                       \
        f32x4 _h0 = *(const f32x4*)(sm.hsh[_bb] + 16 * w + 0);                \
        f32x4 _h1 = *(const f32x4*)(sm.hsh[_bb] + 16 * w + 4);                \
        f32x4 _h2 = *(const f32x4*)(sm.hsh[_bb] + 16 * w + 8);                \
        f32x4 _h3 = *(const f32x4*)(sm.hsh[_bb] + 16 * w + 12);               \
        float _ha[16];                                                        \
        _ha[0]=_h0[0];  _ha[1]=_h0[1];  _ha[2]=_h0[2];  _ha[3]=_h0[3];        \
        _ha[4]=_h1[0];  _ha[5]=_h1[1];  _ha[6]=_h1[2];  _ha[7]=_h1[3];        \
        _ha[8]=_h2[0];  _ha[9]=_h2[1];  _ha[10]=_h2[2]; _ha[11]=_h2[3];       \
        _ha[12]=_h3[0]; _ha[13]=_h3[1]; _ha[14]=_h3[2]; _ha[15]=_h3[3];       \
        float _s0=0.f,_s1=0.f,_s2=0.f,_s3=0.f,_s4=0.f,_s5=0.f;                \
        _Pragma("unroll")                                                     \
        for (int _i = 0; _i < 16; ++_i) {                                     \
            const float _hv = _ha[_i];                                        \
            _s0 = fmaf(_hv, wr[0][_i], _s0); _s1 = fmaf(_hv, wr[1][_i], _s1); \
            _s2 = fmaf(_hv, wr[2][_i], _s2); _s3 = fmaf(_hv, wr[3][_i], _s3); \
            _s4 = fmaf(_hv, wr[4][_i], _s4); _s5 = fmaf(_hv, wr[5][_i], _s5); \
        }                                                                     \
        *(f32x2*)&sm.hp[_bb][w][g6 + 0] = (f32x2){_s0, _s1};                  \
        *(f32x2*)&sm.hp[_bb][w][g6 + 2] = (f32x2){_s2, _s3};                  \
        *(f32x2*)&sm.hp[_bb][w][g6 + 4] = (f32x2){_s4, _s5};                  \
    }                                                                         \
    const bool _pub = isL0 && _t > 0 && (_t & 15) == 0;                       \
    if (_pub && tid < 256) asm volatile("s_waitcnt vmcnt(12)" ::: "memory");  \
    bar_lds();                                                                \
    if (_pub && (tid == 0 || tid == 128)) {                                   \
        __threadfence();                                                      \
        atomicExch(&setflag[b2 * 32 + ((_t >> 4) - 1)], 1);                   \
    }                                                                         \
    if (tid < 256) {                                                          \
        const int _c = tid & 127;                                             \
        float _hr = bhr, _hz = bhz, _hn = bhn;                                \
        _Pragma("unroll")                                                     \
        for (int _q = 0; _q < 8; ++_q) {                                      \
            _hr += sm.hp[half][_q][_c];                                       \
            _hz += sm.hp[half][_q][128 + _c];                                 \
            _hn += sm.hp[half][_q][256 + _c];                                 \
        }                                                                     \
        const float _xr = BUF[(J) * 3 + 0];                                   \
        const float _xz = BUF[(J) * 3 + 1];                                   \
        const float _xn = BUF[(J) * 3 + 2];                                   \
        const float _r = 1.f / (1.f + __expf(-(_xr + _hr)));                  \
        const float _z = 1.f / (1.f + __expf(-(_xz + _hz)));                  \
        float _a = _xn + _r * _hn;                                            \
        _a = fminf(fmaxf(_a, -15.f), 15.f);                                   \
        const float _e = __expf(2.f * _a);                                    \
        const float _n = (_e - 1.f) / (_e + 1.f);                             \
        hreg = (1.f - _z) * _n + _z * hreg;                                   \
        sm.hsh[half][_c] = hreg;                                              \
        if (isL0) hseq[((size_t)(b2 * 512 + _t)) * 128 + _c] = hreg;          \
    }                                                                         \
    bar_lds();                                                                \
} while (0)

__device__ void recur_role(
    bool isL0, int b, const float* __restrict__ xg,
    const float* __restrict__ whh, const float* __restrict__ bhh,
    float* __restrict__ hseq, int* __restrict__ setflag, int* __restrict__ waitflag,
    const float* __restrict__ wfc1, const float* __restrict__ bfc1,
    const float* __restrict__ wfc2, const float* __restrict__ bfc2,
    float* __restrict__ out, SmemRecur& sm)
{
    const int tid  = threadIdx.x;       // 0..511
    const int w    = tid >> 6;          // k-slice 0..7 (wave-uniform)
    const int lane = tid & 63;
    const int g6   = 6 * lane;          // first of this lane's 6 gates
    const int half = (tid >> 7) & 1;    // phase-B batch select (valid tid<256)
    const int b2   = 2 * b + half;      // this thread's batch for B duties

    // per-lane weights (SHARED by both batches): wr[j][i] = whh[(g6+j)*128+16w+i]
    float wr[6][16];
#pragma unroll
    for (int j = 0; j < 6; ++j) {
        const float* p = whh + (size_t)(g6 + j) * 128 + 16 * w;
#pragma unroll
        for (int i4 = 0; i4 < 4; ++i4) {
            f32x4 v = *(const f32x4*)(p + 4 * i4);
            wr[j][4*i4+0] = v[0]; wr[j][4*i4+1] = v[1];
            wr[j][4*i4+2] = v[2]; wr[j][4*i4+3] = v[3];
        }
    }
    float bhr = 0.f, bhz = 0.f, bhn = 0.f, hreg = 0.f;
    if (tid < 256) {
        const int c = tid & 127;
        bhr = bhh[c]; bhz = bhh[128 + c]; bhn = bhh[256 + c];
        sm.hsh[half][c] = 0.f;
    }
    const float* xgb2 = xg + (size_t)b2 * 512 * 384;

    float pA[12], pB[12];
    R_ISSUE(pA, 0);
    R_ISSUE(pB, 1);
    __syncthreads();   // hsh init visible

    for (int gp = 0; gp < 64; ++gp) {
        const int t0 = gp * 8;
        R_STEP(t0 + 0, pA, 0); R_STEP(t0 + 1, pA, 1);
        R_STEP(t0 + 2, pA, 2); R_STEP(t0 + 3, pA, 3);
        R_ISSUE(pA, 2 * gp + 2);
        R_STEP(t0 + 4, pB, 0); R_STEP(t0 + 5, pB, 1);
        R_STEP(t0 + 6, pB, 2); R_STEP(t0 + 7, pB, 3);
        R_ISSUE(pB, 2 * gp + 3);
    }

    if (isL0) {   // final chunk publish (both batches)
        if (tid < 256) asm volatile("s_waitcnt vmcnt(0)" ::: "memory");
        __syncthreads();
        if (tid == 0 || tid == 128) {
            __threadfence();
            atomicExch(&setflag[b2 * 32 + 31], 1);
        }
    }

    if (!isL0) {   // fused MLP heads: batch0 on wave 0, batch1 on wave 2
        const bool headw = (tid < 64) || (tid >= 128 && tid < 192);
        if (headw) {
            const int l_ = tid & 63;
            const float* hv = sm.hsh[half];
            const float* wv = wfc1 + l_ * 128;
            float acc = bfc1[l_];
#pragma unroll 8
            for (int c = 0; c < 128; ++c) acc = fmaf(hv[c], wv[c], acc);
            float p = fmaxf(acc, 0.f) * wfc2[l_];
#pragma unroll
            for (int off = 32; off > 0; off >>= 1) p += __shfl_down(p, off);
            if (l_ == 0) out[b2] = p + bfc2[0];
        }
    }
}

__device__ void worker_role(
    int wk, const float* __restrict__ h1, float* __restrict__ xg,
    const float* __restrict__ wih1, const float* __restrict__ bih1,
    int* __restrict__ h1flag, int* __restrict__ xgflag, SmemGemm& sm)
{
    const int tid = threadIdx.x, lane = tid & 63, w = tid >> 6;   // 8 waves
    const int rsel = lane & 15, koff = (lane >> 4) * 8;

    // persistent W_ih1 fragments: wave w owns n-frags {3w, 3w+1, 3w+2}
    s16x8 bh[3][4], bl[3][4];
    float bias[3];
#pragma unroll
    for (int nfi = 0; nfi < 3; ++nfi) {
        const int n = (3 * w + nfi) * 16 + rsel;
        bias[nfi] = bih1[n];
#pragma unroll
        for (int ks = 0; ks < 4; ++ks) {
            const float* p = wih1 + n * 128 + ks * 32 + koff;
            f32x4 v0 = *(const f32x4*)p, v1 = *(const f32x4*)(p + 4);
            float fv[8] = {v0[0],v0[1],v0[2],v0[3], v1[0],v1[1],v1[2],v1[3]};
            s16x8 hh, ll;
#pragma unroll
            for (int i = 0; i < 8; ++i) {
                u16 h = f2bf(fv[i]); hh[i] = (short)h; ll[i] = (short)f2bf(fv[i] - bf2f(h));
            }
            bh[nfi][ks] = hh; bl[nfi][ks] = ll;
        }
    }

    for (int jt = wk; jt < 2048; jt += 192) {
        const int c = jt >> 6, b = jt & 63;     // chunk 0..31, batch 0..63
        if (tid == 0) {
            while (atomicAdd(&h1flag[b * 32 + c], 0) == 0) __builtin_amdgcn_s_sleep(8);
            __threadfence();
        }
        __syncthreads();
        // stage A = h1 rows (b, 16c..16c+15): fp32 -> split bf16 hi/lo in LDS
        if (tid < 256) {
            const int r = tid >> 4, c0 = (tid & 15) * 8;
            const float* p = h1 + ((size_t)(b * 512 + c * 16 + r)) * 128 + c0;
            f32x4 v0 = *(const f32x4*)p, v1 = *(const f32x4*)(p + 4);
            float fv[8] = {v0[0],v0[1],v0[2],v0[3], v1[0],v1[1],v1[2],v1[3]};
            s16x8 hh, ll;
#pragma unroll
            for (int i = 0; i < 8; ++i) {
                u16 h = f2bf(fv[i]); hh[i] = (short)h; ll[i] = (short)f2bf(fv[i] - bf2f(h));
            }
            const int sc = c0 ^ ((r & 7) << 3);   // XOR-swizzle (T2)
            *(s16x8*)&sm.ah[r * 128 + sc] = hh;
            *(s16x8*)&sm.al[r * 128 + sc] = ll;
        }
        __syncthreads();

        f32x4 acc[3];
        const f32x4 vz = {0.f, 0.f, 0.f, 0.f};
        acc[0] = vz; acc[1] = vz; acc[2] = vz;
#pragma unroll
        for (int ks = 0; ks < 4; ++ks) {
            const int si = rsel * 128 + ((ks * 32 + koff) ^ ((rsel & 7) << 3));
            s16x8 a_h = *(const s16x8*)&sm.ah[si];
            s16x8 a_l = *(const s16x8*)&sm.al[si];
#pragma unroll
            for (int nfi = 0; nfi < 3; ++nfi) {
                acc[nfi] = __builtin_amdgcn_mfma_f32_16x16x32_bf16(a_h, bh[nfi][ks], acc[nfi], 0, 0, 0);
                acc[nfi] = __builtin_amdgcn_mfma_f32_16x16x32_bf16(a_h, bl[nfi][ks], acc[nfi], 0, 0, 0);
                acc[nfi] = __builtin_amdgcn_mfma_f32_16x16x32_bf16(a_l, bh[nfi][ks], acc[nfi], 0, 0, 0);
            }
        }
        // epilogue: xg1 rows overwrite consumed xg0 rows (safe: flag order)
#pragma unroll
        for (int nfi = 0; nfi < 3; ++nfi) {
            const int n = (3 * w + nfi) * 16 + rsel;
#pragma unroll
            for (int jj = 0; jj < 4; ++jj) {
                const int m = (lane >> 4) * 4 + jj;
                xg[((size_t)(b * 512 + c * 16 + m)) * 384 + n] = acc[nfi][jj] + bias[nfi];
            }
        }
        __syncthreads();   // drains stores (vmcnt0) + LDS reuse safety
        if (tid == 0) {
            __threadfence();
            atomicExch(&xgflag[b * 32 + c], 1);
        }
    }
}

__global__ __launch_bounds__(512, 2)
void k_fused(float* __restrict__ xg, float* __restrict__ h1,
             const float* __restrict__ whh0, const float* __restrict__ bhh0,
             const float* __restrict__ wih1, const float* __restrict__ bih1,
             const float* __restrict__ whh1, const float* __restrict__ bhh1,
             const float* __restrict__ wfc1, const float* __restrict__ bfc1,
             const float* __restrict__ wfc2, const float* __restrict__ bfc2,
             float* __restrict__ out, int* __restrict__ h1flag, int* __restrict__ xgflag)
{
    __shared__ __align__(16) Smem sm;
    const int bid = blockIdx.x;
    if (bid < 32) {
        recur_role(true, bid, xg, whh0, bhh0, h1, h1flag, nullptr,
                   nullptr, nullptr, nullptr, nullptr, nullptr, sm.r);
    } else if (bid < 64) {
        recur_role(false, bid - 32, xg, whh1, bhh1, nullptr, nullptr, xgflag,
                   wfc1, bfc1, wfc2, bfc2, out, sm.r);
    } else {
        worker_role(bid - 64, h1, xg, wih1, bih1, h1flag, xgflag, sm.g);
    }
}

extern "C" void kernel_launch(void* const* d_in, const int* in_sizes, int n_in,
                              void* d_out, int out_size, void* d_ws, size_t ws_size,
                              hipStream_t stream) {
    const float* x     = (const float*)d_in[0];
    const float* w_ih0 = (const float*)d_in[1];
    const float* w_hh0 = (const float*)d_in[2];
    const float* b_ih0 = (const float*)d_in[3];
    const float* b_hh0 = (const float*)d_in[4];
    const float* w_ih1 = (const float*)d_in[5];
    const float* w_hh1 = (const float*)d_in[6];
    const float* b_ih1 = (const float*)d_in[7];
    const float* b_hh1 = (const float*)d_in[8];
    const float* w_fc1 = (const float*)d_in[9];
    const float* b_fc1 = (const float*)d_in[10];
    const float* w_fc2 = (const float*)d_in[11];
    const float* b_fc2 = (const float*)d_in[12];
    float* out = (float*)d_out;
    (void)in_sizes; (void)n_in; (void)out_size; (void)ws_size;

    char* ws = (char*)d_ws;
    float* xg     = (float*)(ws + 0);          // 32768*384*4 (xg0, then xg1 in place)
    float* h1     = (float*)(ws + 50331648);   // 32768*128*4
    u16*   w0h    = (u16*)(ws + 67108864);     // 786432*2
    u16*   w0l    = (u16*)(ws + 68681728);     // 786432*2
    int*   h1flag = (int*)(ws + 70254592);     // 2048 ints
    int*   xgflag = h1flag + 2048;             // 2048 ints

    k_zero<<<16, 256, 0, stream>>>(h1flag, 4096);
    k_split<<<3072, 256, 0, stream>>>(w_ih0, w0h, w0l, 384 * 2048);
    k_gemm<<<768, 256, 0, stream>>>(x, w0h, w0l, b_ih0, xg, 2048);
    k_fused<<<256, 512, 0, stream>>>(xg, h1, w_hh0, b_hh0, w_ih1, b_ih1,
                                     w_hh1, b_hh1, w_fc1, b_fc1, w_fc2, b_fc2,
                                     out, h1flag, xgflag);
}